// Round 7
// baseline (567.824 us; speedup 1.0000x reference)
//
#include <hip/hip_runtime.h>
#include <hip/hip_bf16.h>
#include <math.h>

#define N_JOINTS 24
#define N_VERTS 6890

__constant__ int c_par[24] = {0, 0, 0, 0, 1, 2, 3, 4, 5, 6, 7, 8, 9, 9, 9,
                              12, 13, 14, 16, 17, 18, 19, 20, 21};

// ---------------------------------------------------------------------------
// K1: fold J_regressor into shapedirs / v_template.
// SD_J[j][c][k] = sum_v Jreg[j][v]*sd[v][c][k];  Jt[j][c] = sum_v Jreg[j][v]*vt[v][c]
__global__ void k1_regress(const float* __restrict__ Jreg,
                           const float* __restrict__ sd,
                           const float* __restrict__ vt,
                           float* __restrict__ SD_J,
                           float* __restrict__ Jt) {
    int j = blockIdx.x / 3;
    int c = blockIdx.x % 3;
    float acc[11];
#pragma unroll
    for (int k = 0; k < 11; k++) acc[k] = 0.f;

    for (int v = threadIdx.x; v < N_VERTS; v += 256) {
        float r = Jreg[j * N_VERTS + v];
        const float* sdp = sd + ((size_t)v * 3 + c) * 10;
#pragma unroll
        for (int k = 0; k < 10; k++) acc[k] += r * sdp[k];
        acc[10] += r * vt[v * 3 + c];
    }
#pragma unroll
    for (int k = 0; k < 11; k++) {
        float x = acc[k];
        for (int off = 32; off > 0; off >>= 1) x += __shfl_down(x, off);
        acc[k] = x;
    }
    __shared__ float red[4][11];
    int lane = threadIdx.x & 63, wid = threadIdx.x >> 6;
    if (lane == 0) {
#pragma unroll
        for (int k = 0; k < 11; k++) red[wid][k] = acc[k];
    }
    __syncthreads();
    if (threadIdx.x == 0) {
#pragma unroll
        for (int k = 0; k < 11; k++) {
            float s = red[0][k] + red[1][k] + red[2][k] + red[3][k];
            if (k < 10) SD_J[(j * 3 + c) * 10 + k] = s;
            else        Jt[j * 3 + c] = s;
        }
    }
}

// ---------------------------------------------------------------------------
// K2: per-sample joints + rodrigues + FK.  grid = N, block = 64.
// Gout [N][24][12] (3x4, rest pose removed), lrot [N][208] (207 used)
__global__ void k2_fk(const float* __restrict__ betas,
                      const float* __restrict__ thetas,
                      const float* __restrict__ SD_J,
                      const float* __restrict__ Jt,
                      float* __restrict__ Gout,
                      float* __restrict__ lrot) {
    int n = blockIdx.x;
    int j = threadIdx.x;

    __shared__ float bsh[10];
    __shared__ float Jl[24][3];
    __shared__ float A[24][12];
    __shared__ float Gs[24][12];

    if (threadIdx.x < 10) bsh[threadIdx.x] = betas[n * 10 + threadIdx.x];
    __syncthreads();

    if (j < 24) {
#pragma unroll
        for (int c = 0; c < 3; c++) {
            float s = Jt[j * 3 + c];
            const float* sp = SD_J + (j * 3 + c) * 10;
#pragma unroll
            for (int k = 0; k < 10; k++) s += bsh[k] * sp[k];
            Jl[j][c] = s;
        }
    }
    __syncthreads();

    if (j < 24) {
        float rx = thetas[n * 72 + j * 3 + 0];
        float ry = thetas[n * 72 + j * 3 + 1];
        float rz = thetas[n * 72 + j * 3 + 2];
        float th = sqrtf(rx * rx + ry * ry + rz * rz) + 1e-8f;
        float inv = 1.f / th;
        float hx = rx * inv, hy = ry * inv, hz = rz * inv;
        float ct = cosf(th), st = sinf(th), omc = 1.f - ct;
        float R[3][3];
        R[0][0] = ct + omc * hx * hx;
        R[0][1] = omc * hx * hy - st * hz;
        R[0][2] = omc * hx * hz + st * hy;
        R[1][0] = omc * hx * hy + st * hz;
        R[1][1] = ct + omc * hy * hy;
        R[1][2] = omc * hy * hz - st * hx;
        R[2][0] = omc * hx * hz - st * hy;
        R[2][1] = omc * hy * hz + st * hx;
        R[2][2] = ct + omc * hz * hz;

        if (j >= 1) {
            float* lp = lrot + (size_t)n * 208 + (j - 1) * 9;
#pragma unroll
            for (int r = 0; r < 3; r++)
#pragma unroll
                for (int c = 0; c < 3; c++)
                    lp[r * 3 + c] = R[r][c] - ((r == c) ? 1.f : 0.f);
        }
        float tx, ty, tz;
        if (j == 0) { tx = Jl[0][0]; ty = Jl[0][1]; tz = Jl[0][2]; }
        else {
            int p = c_par[j];
            tx = Jl[j][0] - Jl[p][0];
            ty = Jl[j][1] - Jl[p][1];
            tz = Jl[j][2] - Jl[p][2];
        }
#pragma unroll
        for (int r = 0; r < 3; r++) {
            A[j][r * 4 + 0] = R[r][0];
            A[j][r * 4 + 1] = R[r][1];
            A[j][r * 4 + 2] = R[r][2];
        }
        A[j][3] = tx; A[j][7] = ty; A[j][11] = tz;
    }
    __syncthreads();

    if (threadIdx.x == 0) {
#pragma unroll
        for (int q = 0; q < 12; q++) Gs[0][q] = A[0][q];
        for (int i = 1; i < 24; i++) {
            int p = c_par[i];
#pragma unroll
            for (int r = 0; r < 3; r++) {
                float g0 = Gs[p][r * 4 + 0], g1 = Gs[p][r * 4 + 1];
                float g2 = Gs[p][r * 4 + 2], g3 = Gs[p][r * 4 + 3];
#pragma unroll
                for (int c = 0; c < 4; c++) {
                    float s = g0 * A[i][0 * 4 + c] + g1 * A[i][1 * 4 + c] +
                              g2 * A[i][2 * 4 + c];
                    if (c == 3) s += g3;
                    Gs[i][r * 4 + c] = s;
                }
            }
        }
    }
    __syncthreads();

    if (j < 24) {
        float jx = Jl[j][0], jy = Jl[j][1], jz = Jl[j][2];
        float* gp = Gout + (size_t)n * 288 + j * 12;
#pragma unroll
        for (int r = 0; r < 3; r++) {
            float r0 = Gs[j][r * 4 + 0], r1 = Gs[j][r * 4 + 1];
            float r2 = Gs[j][r * 4 + 2], t = Gs[j][r * 4 + 3];
            gp[r * 4 + 0] = r0;
            gp[r * 4 + 1] = r1;
            gp[r * 4 + 2] = r2;
            gp[r * 4 + 3] = t - (r0 * jx + r1 * jy + r2 * jz);
        }
    }
}

// ---------------------------------------------------------------------------
// K3: heavy skinning.  block = 256 = 64 verts x 4 sample-groups; each thread
// handles 4 samples (16 samples/block).  grid = (N/16, ceil(V/64))
__global__ void __launch_bounds__(256)
k3_skin(const float* __restrict__ betas,
        const float* __restrict__ trans,
        const float* __restrict__ v_template,
        const float* __restrict__ shapedirs,
        const float* __restrict__ posedirs,
        const float* __restrict__ weights,
        const float* __restrict__ G_ws,
        const float* __restrict__ lrot_ws,
        float* __restrict__ out) {
    __shared__ float Llrot[16][208];
    __shared__ float Lg[16][288];
    __shared__ float Lbet[16][10];
    __shared__ float Ltrans[16][3];

    const int tid = threadIdx.x;
    const int nbase = blockIdx.x * 16;
    const int vbase = blockIdx.y * 64;

    for (int idx = tid; idx < 16 * 207; idx += 256) {
        int s = idx / 207, p = idx % 207;
        Llrot[s][p] = lrot_ws[(size_t)(nbase + s) * 208 + p];
    }
    for (int idx = tid; idx < 16 * 288; idx += 256) {
        int s = idx / 288, q = idx % 288;
        Lg[s][q] = G_ws[(size_t)(nbase + s) * 288 + q];
    }
    for (int idx = tid; idx < 160; idx += 256)
        Lbet[idx / 10][idx % 10] = betas[(nbase + idx / 10) * 10 + idx % 10];
    for (int idx = tid; idx < 48; idx += 256)
        Ltrans[idx / 3][idx % 3] = trans[(nbase + idx / 3) * 3 + idx % 3];
    __syncthreads();

    const int vt_i = tid & 63;
    const int ng = tid >> 6;
    const int v = vbase + vt_i;
    if (v >= N_VERTS) return;
    const int s0 = ng * 4;

    float acc[4][3];
    {
        float t0 = v_template[v * 3 + 0];
        float t1 = v_template[v * 3 + 1];
        float t2 = v_template[v * 3 + 2];
#pragma unroll
        for (int i = 0; i < 4; i++) {
            acc[i][0] = t0; acc[i][1] = t1; acc[i][2] = t2;
        }
    }
    {
        const float* sdp = shapedirs + (size_t)v * 30;
#pragma unroll
        for (int k = 0; k < 10; k++) {
            float s0v = sdp[k];
            float s1v = sdp[10 + k];
            float s2v = sdp[20 + k];
#pragma unroll
            for (int i = 0; i < 4; i++) {
                float b = Lbet[s0 + i][k];
                acc[i][0] += b * s0v;
                acc[i][1] += b * s1v;
                acc[i][2] += b * s2v;
            }
        }
    }
    {
        const float* pdp = posedirs + (size_t)v * 621;
        for (int p = 0; p < 207; p++) {
            float p0 = pdp[p];
            float p1 = pdp[207 + p];
            float p2 = pdp[414 + p];
#pragma unroll
            for (int i = 0; i < 4; i++) {
                float l = Llrot[s0 + i][p];
                acc[i][0] += l * p0;
                acc[i][1] += l * p1;
                acc[i][2] += l * p2;
            }
        }
    }
    float w[24];
#pragma unroll
    for (int j = 0; j < 24; j++) w[j] = weights[(size_t)v * 24 + j];

#pragma unroll
    for (int i = 0; i < 4; i++) {
        int s = s0 + i;
        float T[12];
#pragma unroll
        for (int q = 0; q < 12; q++) T[q] = 0.f;
        for (int j = 0; j < 24; j++) {
            float wj = w[j];
            const float* g = &Lg[s][j * 12];
#pragma unroll
            for (int q = 0; q < 12; q++) T[q] += wj * g[q];
        }
        float x = acc[i][0], y = acc[i][1], z = acc[i][2];
        float o0 = T[0] * x + T[1] * y + T[2]  * z + T[3]  + Ltrans[s][0];
        float o1 = T[4] * x + T[5] * y + T[6]  * z + T[7]  + Ltrans[s][1];
        float o2 = T[8] * x + T[9] * y + T[10] * z + T[11] + Ltrans[s][2];
        int n = nbase + s;
        float* op = out + ((size_t)n * N_VERTS + v) * 3;
        op[0] = o0;
        op[1] = o1;
        op[2] = o2;
    }
}

// ---------------------------------------------------------------------------
// K4: joints[n][j][c] = sum_v result[n][v][c] * jreg[v][j].  grid = N.
__global__ void k4_joints(const float* __restrict__ result,
                          const float* __restrict__ jreg,
                          float* __restrict__ outj) {
    int n = blockIdx.x;
    int tid = threadIdx.x;
    float acc[72];
#pragma unroll
    for (int q = 0; q < 72; q++) acc[q] = 0.f;

    for (int v = tid; v < N_VERTS; v += 256) {
        const float* rp = result + ((size_t)n * N_VERTS + v) * 3;
        float r0 = rp[0], r1 = rp[1], r2 = rp[2];
        const float* jr = jreg + (size_t)v * 24;
#pragma unroll
        for (int j = 0; j < 24; j++) {
            float wv = jr[j];
            acc[j * 3 + 0] += wv * r0;
            acc[j * 3 + 1] += wv * r1;
            acc[j * 3 + 2] += wv * r2;
        }
    }
#pragma unroll
    for (int q = 0; q < 72; q++) {
        float x = acc[q];
        for (int off = 32; off > 0; off >>= 1) x += __shfl_down(x, off);
        acc[q] = x;
    }
    __shared__ float red[4][72];
    int lane = tid & 63, wid = tid >> 6;
    if (lane == 0) {
#pragma unroll
        for (int q = 0; q < 72; q++) red[wid][q] = acc[q];
    }
    __syncthreads();
    if (tid < 72) {
        float s = red[0][tid] + red[1][tid] + red[2][tid] + red[3][tid];
        outj[(size_t)n * 72 + tid] = s;
    }
}

// ---------------------------------------------------------------------------
extern "C" void kernel_launch(void* const* d_in, const int* in_sizes, int n_in,
                              void* d_out, int out_size, void* d_ws, size_t ws_size,
                              hipStream_t stream) {
    const float* betas     = (const float*)d_in[0];
    const float* thetas    = (const float*)d_in[1];
    const float* trans     = (const float*)d_in[2];
    const float* v_templ   = (const float*)d_in[3];
    const float* shapedirs = (const float*)d_in[4];
    const float* posedirs  = (const float*)d_in[5];
    const float* Jreg      = (const float*)d_in[6];
    const float* jointreg  = (const float*)d_in[7];
    const float* weights   = (const float*)d_in[8];

    // Output is FLOAT32 (R6 probe evidence): result [N,V,3] then joints [N,24,3].
    float* out = (float*)d_out;

    const int N = in_sizes[0] / 10;   // 512

    float* ws = (float*)d_ws;
    float* SD_J  = ws;                 // 720
    float* Jt    = ws + 720;           // 72
    float* G_ws  = ws + 800;           // N*288
    float* lrot  = ws + 800 + (size_t)N * 288;  // N*208

    k1_regress<<<72, 256, 0, stream>>>(Jreg, shapedirs, v_templ, SD_J, Jt);
    k2_fk<<<N, 64, 0, stream>>>(betas, thetas, SD_J, Jt, G_ws, lrot);
    dim3 g3(N / 16, (N_VERTS + 63) / 64);
    k3_skin<<<g3, 256, 0, stream>>>(betas, trans, v_templ, shapedirs, posedirs,
                                    weights, G_ws, lrot, out);
    float* outj = out + (size_t)N * N_VERTS * 3;
    k4_joints<<<N, 256, 0, stream>>>(out, jointreg, outj);
}

// Round 8
// 393.313 us; speedup vs baseline: 1.4437x; 1.4437x over previous
//
#include <hip/hip_runtime.h>
#include <hip/hip_bf16.h>
#include <math.h>

#define N_JOINTS 24
#define N_VERTS 6890

__constant__ int c_par[24] = {0, 0, 0, 0, 1, 2, 3, 4, 5, 6, 7, 8, 9, 9, 9,
                              12, 13, 14, 16, 17, 18, 19, 20, 21};

// ---------------------------------------------------------------------------
// T0: transpose [NV][C] -> [C][NV].  Writes coalesced (v fastest), reads
// strided (one-time cost).  total = C*NV elements.
__global__ void t_transpose(const float* __restrict__ src,
                            float* __restrict__ dst, int C, int total) {
    int idx = blockIdx.x * 256 + threadIdx.x;
    if (idx >= total) return;
    int c = idx / N_VERTS;
    int v = idx - c * N_VERTS;
    dst[idx] = src[(size_t)v * C + c];
}

// ---------------------------------------------------------------------------
// K1: fold J_regressor into shapedirs / v_template.
__global__ void k1_regress(const float* __restrict__ Jreg,
                           const float* __restrict__ sd,
                           const float* __restrict__ vt,
                           float* __restrict__ SD_J,
                           float* __restrict__ Jt) {
    int j = blockIdx.x / 3;
    int c = blockIdx.x % 3;
    float acc[11];
#pragma unroll
    for (int k = 0; k < 11; k++) acc[k] = 0.f;

    for (int v = threadIdx.x; v < N_VERTS; v += 256) {
        float r = Jreg[j * N_VERTS + v];
        const float* sdp = sd + ((size_t)v * 3 + c) * 10;
#pragma unroll
        for (int k = 0; k < 10; k++) acc[k] += r * sdp[k];
        acc[10] += r * vt[v * 3 + c];
    }
#pragma unroll
    for (int k = 0; k < 11; k++) {
        float x = acc[k];
        for (int off = 32; off > 0; off >>= 1) x += __shfl_down(x, off);
        acc[k] = x;
    }
    __shared__ float red[4][11];
    int lane = threadIdx.x & 63, wid = threadIdx.x >> 6;
    if (lane == 0) {
#pragma unroll
        for (int k = 0; k < 11; k++) red[wid][k] = acc[k];
    }
    __syncthreads();
    if (threadIdx.x == 0) {
#pragma unroll
        for (int k = 0; k < 11; k++) {
            float s = red[0][k] + red[1][k] + red[2][k] + red[3][k];
            if (k < 10) SD_J[(j * 3 + c) * 10 + k] = s;
            else        Jt[j * 3 + c] = s;
        }
    }
}

// ---------------------------------------------------------------------------
// K2: per-sample joints + rodrigues + FK.  grid = N, block = 64.
__global__ void k2_fk(const float* __restrict__ betas,
                      const float* __restrict__ thetas,
                      const float* __restrict__ SD_J,
                      const float* __restrict__ Jt,
                      float* __restrict__ Gout,
                      float* __restrict__ lrot) {
    int n = blockIdx.x;
    int j = threadIdx.x;

    __shared__ float bsh[10];
    __shared__ float Jl[24][3];
    __shared__ float A[24][12];
    __shared__ float Gs[24][12];

    if (threadIdx.x < 10) bsh[threadIdx.x] = betas[n * 10 + threadIdx.x];
    __syncthreads();

    if (j < 24) {
#pragma unroll
        for (int c = 0; c < 3; c++) {
            float s = Jt[j * 3 + c];
            const float* sp = SD_J + (j * 3 + c) * 10;
#pragma unroll
            for (int k = 0; k < 10; k++) s += bsh[k] * sp[k];
            Jl[j][c] = s;
        }
    }
    __syncthreads();

    if (j < 24) {
        float rx = thetas[n * 72 + j * 3 + 0];
        float ry = thetas[n * 72 + j * 3 + 1];
        float rz = thetas[n * 72 + j * 3 + 2];
        float th = sqrtf(rx * rx + ry * ry + rz * rz) + 1e-8f;
        float inv = 1.f / th;
        float hx = rx * inv, hy = ry * inv, hz = rz * inv;
        float ct = cosf(th), st = sinf(th), omc = 1.f - ct;
        float R[3][3];
        R[0][0] = ct + omc * hx * hx;
        R[0][1] = omc * hx * hy - st * hz;
        R[0][2] = omc * hx * hz + st * hy;
        R[1][0] = omc * hx * hy + st * hz;
        R[1][1] = ct + omc * hy * hy;
        R[1][2] = omc * hy * hz - st * hx;
        R[2][0] = omc * hx * hz - st * hy;
        R[2][1] = omc * hy * hz + st * hx;
        R[2][2] = ct + omc * hz * hz;

        if (j >= 1) {
            float* lp = lrot + (size_t)n * 208 + (j - 1) * 9;
#pragma unroll
            for (int r = 0; r < 3; r++)
#pragma unroll
                for (int c = 0; c < 3; c++)
                    lp[r * 3 + c] = R[r][c] - ((r == c) ? 1.f : 0.f);
        }
        float tx, ty, tz;
        if (j == 0) { tx = Jl[0][0]; ty = Jl[0][1]; tz = Jl[0][2]; }
        else {
            int p = c_par[j];
            tx = Jl[j][0] - Jl[p][0];
            ty = Jl[j][1] - Jl[p][1];
            tz = Jl[j][2] - Jl[p][2];
        }
#pragma unroll
        for (int r = 0; r < 3; r++) {
            A[j][r * 4 + 0] = R[r][0];
            A[j][r * 4 + 1] = R[r][1];
            A[j][r * 4 + 2] = R[r][2];
        }
        A[j][3] = tx; A[j][7] = ty; A[j][11] = tz;
    }
    __syncthreads();

    if (threadIdx.x == 0) {
#pragma unroll
        for (int q = 0; q < 12; q++) Gs[0][q] = A[0][q];
        for (int i = 1; i < 24; i++) {
            int p = c_par[i];
#pragma unroll
            for (int r = 0; r < 3; r++) {
                float g0 = Gs[p][r * 4 + 0], g1 = Gs[p][r * 4 + 1];
                float g2 = Gs[p][r * 4 + 2], g3 = Gs[p][r * 4 + 3];
#pragma unroll
                for (int c = 0; c < 4; c++) {
                    float s = g0 * A[i][0 * 4 + c] + g1 * A[i][1 * 4 + c] +
                              g2 * A[i][2 * 4 + c];
                    if (c == 3) s += g3;
                    Gs[i][r * 4 + c] = s;
                }
            }
        }
    }
    __syncthreads();

    if (j < 24) {
        float jx = Jl[j][0], jy = Jl[j][1], jz = Jl[j][2];
        float* gp = Gout + (size_t)n * 288 + j * 12;
#pragma unroll
        for (int r = 0; r < 3; r++) {
            float r0 = Gs[j][r * 4 + 0], r1 = Gs[j][r * 4 + 1];
            float r2 = Gs[j][r * 4 + 2], t = Gs[j][r * 4 + 3];
            gp[r * 4 + 0] = r0;
            gp[r * 4 + 1] = r1;
            gp[r * 4 + 2] = r2;
            gp[r * 4 + 3] = t - (r0 * jx + r1 * jy + r2 * jz);
        }
    }
}

// ---------------------------------------------------------------------------
// K3T: skinning with TRANSPOSED posedirs [621][NV] and weights [24][NV].
// All global reads coalesced (lane = vertex).  block = 256 = 64 verts x 4
// sample-groups; each thread: 4 samples.  grid = (N/16, ceil(V/64))
__global__ void __launch_bounds__(256)
k3_skin_t(const float* __restrict__ betas,
          const float* __restrict__ trans,
          const float* __restrict__ v_template,
          const float* __restrict__ shapedirs,
          const float* __restrict__ pd_t,    // [621][NV]
          const float* __restrict__ w_t,     // [24][NV]
          const float* __restrict__ G_ws,
          const float* __restrict__ lrot_ws,
          float* __restrict__ out) {
    __shared__ float Llrot[16][208];
    __shared__ float Lg[16][288];
    __shared__ float Lbet[16][10];
    __shared__ float Ltrans[16][3];

    const int tid = threadIdx.x;
    const int nbase = blockIdx.x * 16;
    const int vbase = blockIdx.y * 64;

    for (int idx = tid; idx < 16 * 207; idx += 256) {
        int s = idx / 207, p = idx % 207;
        Llrot[s][p] = lrot_ws[(size_t)(nbase + s) * 208 + p];
    }
    for (int idx = tid; idx < 16 * 288; idx += 256) {
        int s = idx / 288, q = idx % 288;
        Lg[s][q] = G_ws[(size_t)(nbase + s) * 288 + q];
    }
    for (int idx = tid; idx < 160; idx += 256)
        Lbet[idx / 10][idx % 10] = betas[(nbase + idx / 10) * 10 + idx % 10];
    for (int idx = tid; idx < 48; idx += 256)
        Ltrans[idx / 3][idx % 3] = trans[(nbase + idx / 3) * 3 + idx % 3];
    __syncthreads();

    const int vt_i = tid & 63;
    const int ng = tid >> 6;          // wave id; all lanes share ng
    const int v = vbase + vt_i;
    if (v >= N_VERTS) return;
    const int s0 = ng * 4;

    float acc[4][3];
    {
        float t0 = v_template[v * 3 + 0];
        float t1 = v_template[v * 3 + 1];
        float t2 = v_template[v * 3 + 2];
#pragma unroll
        for (int i = 0; i < 4; i++) {
            acc[i][0] = t0; acc[i][1] = t1; acc[i][2] = t2;
        }
    }
    // shape blend (shapedirs small: 0.83 MB, L2-resident; strided but cheap)
    {
        const float* sdp = shapedirs + (size_t)v * 30;
#pragma unroll
        for (int k = 0; k < 10; k++) {
            float s0v = sdp[k];
            float s1v = sdp[10 + k];
            float s2v = sdp[20 + k];
#pragma unroll
            for (int i = 0; i < 4; i++) {
                float b = Lbet[s0 + i][k];
                acc[i][0] += b * s0v;
                acc[i][1] += b * s1v;
                acc[i][2] += b * s2v;
            }
        }
    }
    // pose blend — coalesced: lane stride 4 B within each [p] slice
    {
        const float* p0p = pd_t + (size_t)0 * 207 * N_VERTS + v;
        const float* p1p = pd_t + (size_t)1 * 207 * N_VERTS + v;
        const float* p2p = pd_t + (size_t)2 * 207 * N_VERTS + v;
        for (int p = 0; p < 207; p++) {
            float p0 = p0p[(size_t)p * N_VERTS];
            float p1 = p1p[(size_t)p * N_VERTS];
            float p2 = p2p[(size_t)p * N_VERTS];
#pragma unroll
            for (int i = 0; i < 4; i++) {
                float l = Llrot[s0 + i][p];   // wave-uniform broadcast
                acc[i][0] += l * p0;
                acc[i][1] += l * p1;
                acc[i][2] += l * p2;
            }
        }
    }
    // LBS — weights coalesced from w_t
    float w[24];
#pragma unroll
    for (int j = 0; j < 24; j++) w[j] = w_t[(size_t)j * N_VERTS + v];

#pragma unroll
    for (int i = 0; i < 4; i++) {
        int s = s0 + i;
        float T[12];
#pragma unroll
        for (int q = 0; q < 12; q++) T[q] = 0.f;
        for (int j = 0; j < 24; j++) {
            float wj = w[j];
            const float* g = &Lg[s][j * 12];
#pragma unroll
            for (int q = 0; q < 12; q++) T[q] += wj * g[q];
        }
        float x = acc[i][0], y = acc[i][1], z = acc[i][2];
        float o0 = T[0] * x + T[1] * y + T[2]  * z + T[3]  + Ltrans[s][0];
        float o1 = T[4] * x + T[5] * y + T[6]  * z + T[7]  + Ltrans[s][1];
        float o2 = T[8] * x + T[9] * y + T[10] * z + T[11] + Ltrans[s][2];
        int n = nbase + s;
        float* op = out + ((size_t)n * N_VERTS + v) * 3;
        op[0] = o0;
        op[1] = o1;
        op[2] = o2;
    }
}

// ---------------------------------------------------------------------------
// K4T: joints with TRANSPOSED jointreg [24][NV] — coalesced.
__global__ void k4_joints_t(const float* __restrict__ result,
                            const float* __restrict__ jr_t,
                            float* __restrict__ outj) {
    int n = blockIdx.x;
    int tid = threadIdx.x;
    float acc[72];
#pragma unroll
    for (int q = 0; q < 72; q++) acc[q] = 0.f;

    for (int v = tid; v < N_VERTS; v += 256) {
        const float* rp = result + ((size_t)n * N_VERTS + v) * 3;
        float r0 = rp[0], r1 = rp[1], r2 = rp[2];
#pragma unroll
        for (int j = 0; j < 24; j++) {
            float wv = jr_t[(size_t)j * N_VERTS + v];
            acc[j * 3 + 0] += wv * r0;
            acc[j * 3 + 1] += wv * r1;
            acc[j * 3 + 2] += wv * r2;
        }
    }
#pragma unroll
    for (int q = 0; q < 72; q++) {
        float x = acc[q];
        for (int off = 32; off > 0; off >>= 1) x += __shfl_down(x, off);
        acc[q] = x;
    }
    __shared__ float red[4][72];
    int lane = tid & 63, wid = tid >> 6;
    if (lane == 0) {
#pragma unroll
        for (int q = 0; q < 72; q++) red[wid][q] = acc[q];
    }
    __syncthreads();
    if (tid < 72) {
        float s = red[0][tid] + red[1][tid] + red[2][tid] + red[3][tid];
        outj[(size_t)n * 72 + tid] = s;
    }
}

// ---------------------------------------------------------------------------
// Fallback kernels (round-7, untransposed) in case ws is too small.
__global__ void __launch_bounds__(256)
k3_skin(const float* __restrict__ betas,
        const float* __restrict__ trans,
        const float* __restrict__ v_template,
        const float* __restrict__ shapedirs,
        const float* __restrict__ posedirs,
        const float* __restrict__ weights,
        const float* __restrict__ G_ws,
        const float* __restrict__ lrot_ws,
        float* __restrict__ out) {
    __shared__ float Llrot[16][208];
    __shared__ float Lg[16][288];
    __shared__ float Lbet[16][10];
    __shared__ float Ltrans[16][3];

    const int tid = threadIdx.x;
    const int nbase = blockIdx.x * 16;
    const int vbase = blockIdx.y * 64;

    for (int idx = tid; idx < 16 * 207; idx += 256) {
        int s = idx / 207, p = idx % 207;
        Llrot[s][p] = lrot_ws[(size_t)(nbase + s) * 208 + p];
    }
    for (int idx = tid; idx < 16 * 288; idx += 256) {
        int s = idx / 288, q = idx % 288;
        Lg[s][q] = G_ws[(size_t)(nbase + s) * 288 + q];
    }
    for (int idx = tid; idx < 160; idx += 256)
        Lbet[idx / 10][idx % 10] = betas[(nbase + idx / 10) * 10 + idx % 10];
    for (int idx = tid; idx < 48; idx += 256)
        Ltrans[idx / 3][idx % 3] = trans[(nbase + idx / 3) * 3 + idx % 3];
    __syncthreads();

    const int vt_i = tid & 63;
    const int ng = tid >> 6;
    const int v = vbase + vt_i;
    if (v >= N_VERTS) return;
    const int s0 = ng * 4;

    float acc[4][3];
    {
        float t0 = v_template[v * 3 + 0];
        float t1 = v_template[v * 3 + 1];
        float t2 = v_template[v * 3 + 2];
#pragma unroll
        for (int i = 0; i < 4; i++) {
            acc[i][0] = t0; acc[i][1] = t1; acc[i][2] = t2;
        }
    }
    {
        const float* sdp = shapedirs + (size_t)v * 30;
#pragma unroll
        for (int k = 0; k < 10; k++) {
            float s0v = sdp[k], s1v = sdp[10 + k], s2v = sdp[20 + k];
#pragma unroll
            for (int i = 0; i < 4; i++) {
                float b = Lbet[s0 + i][k];
                acc[i][0] += b * s0v;
                acc[i][1] += b * s1v;
                acc[i][2] += b * s2v;
            }
        }
    }
    {
        const float* pdp = posedirs + (size_t)v * 621;
        for (int p = 0; p < 207; p++) {
            float p0 = pdp[p], p1 = pdp[207 + p], p2 = pdp[414 + p];
#pragma unroll
            for (int i = 0; i < 4; i++) {
                float l = Llrot[s0 + i][p];
                acc[i][0] += l * p0;
                acc[i][1] += l * p1;
                acc[i][2] += l * p2;
            }
        }
    }
    float w[24];
#pragma unroll
    for (int j = 0; j < 24; j++) w[j] = weights[(size_t)v * 24 + j];

#pragma unroll
    for (int i = 0; i < 4; i++) {
        int s = s0 + i;
        float T[12];
#pragma unroll
        for (int q = 0; q < 12; q++) T[q] = 0.f;
        for (int j = 0; j < 24; j++) {
            float wj = w[j];
            const float* g = &Lg[s][j * 12];
#pragma unroll
            for (int q = 0; q < 12; q++) T[q] += wj * g[q];
        }
        float x = acc[i][0], y = acc[i][1], z = acc[i][2];
        float o0 = T[0] * x + T[1] * y + T[2]  * z + T[3]  + Ltrans[s][0];
        float o1 = T[4] * x + T[5] * y + T[6]  * z + T[7]  + Ltrans[s][1];
        float o2 = T[8] * x + T[9] * y + T[10] * z + T[11] + Ltrans[s][2];
        int n = nbase + s;
        float* op = out + ((size_t)n * N_VERTS + v) * 3;
        op[0] = o0; op[1] = o1; op[2] = o2;
    }
}

__global__ void k4_joints(const float* __restrict__ result,
                          const float* __restrict__ jreg,
                          float* __restrict__ outj) {
    int n = blockIdx.x;
    int tid = threadIdx.x;
    float acc[72];
#pragma unroll
    for (int q = 0; q < 72; q++) acc[q] = 0.f;

    for (int v = tid; v < N_VERTS; v += 256) {
        const float* rp = result + ((size_t)n * N_VERTS + v) * 3;
        float r0 = rp[0], r1 = rp[1], r2 = rp[2];
        const float* jr = jreg + (size_t)v * 24;
#pragma unroll
        for (int j = 0; j < 24; j++) {
            float wv = jr[j];
            acc[j * 3 + 0] += wv * r0;
            acc[j * 3 + 1] += wv * r1;
            acc[j * 3 + 2] += wv * r2;
        }
    }
#pragma unroll
    for (int q = 0; q < 72; q++) {
        float x = acc[q];
        for (int off = 32; off > 0; off >>= 1) x += __shfl_down(x, off);
        acc[q] = x;
    }
    __shared__ float red[4][72];
    int lane = tid & 63, wid = tid >> 6;
    if (lane == 0) {
#pragma unroll
        for (int q = 0; q < 72; q++) red[wid][q] = acc[q];
    }
    __syncthreads();
    if (tid < 72) {
        float s = red[0][tid] + red[1][tid] + red[2][tid] + red[3][tid];
        outj[(size_t)n * 72 + tid] = s;
    }
}

// ---------------------------------------------------------------------------
extern "C" void kernel_launch(void* const* d_in, const int* in_sizes, int n_in,
                              void* d_out, int out_size, void* d_ws, size_t ws_size,
                              hipStream_t stream) {
    const float* betas     = (const float*)d_in[0];
    const float* thetas    = (const float*)d_in[1];
    const float* trans     = (const float*)d_in[2];
    const float* v_templ   = (const float*)d_in[3];
    const float* shapedirs = (const float*)d_in[4];
    const float* posedirs  = (const float*)d_in[5];
    const float* Jreg      = (const float*)d_in[6];
    const float* jointreg  = (const float*)d_in[7];
    const float* weights   = (const float*)d_in[8];

    float* out = (float*)d_out;   // fp32: result [N,V,3] then joints [N,24,3]
    const int N = in_sizes[0] / 10;   // 512

    float* ws = (float*)d_ws;
    float* SD_J  = ws;                                   // 720
    float* Jt    = ws + 720;                             // 72
    float* G_ws  = ws + 800;                             // N*288
    float* lrot  = ws + 800 + (size_t)N * 288;           // N*208
    size_t fk_end = 800 + (size_t)N * 288 + (size_t)N * 208;
    float* pd_t  = ws + fk_end;                          // 621*NV
    float* w_t   = pd_t + (size_t)621 * N_VERTS;         // 24*NV
    float* jr_t  = w_t + (size_t)24 * N_VERTS;           // 24*NV
    size_t need  = (fk_end + (size_t)(621 + 24 + 24) * N_VERTS) * 4;

    k1_regress<<<72, 256, 0, stream>>>(Jreg, shapedirs, v_templ, SD_J, Jt);
    k2_fk<<<N, 64, 0, stream>>>(betas, thetas, SD_J, Jt, G_ws, lrot);

    dim3 g3(N / 16, (N_VERTS + 63) / 64);
    float* outj = out + (size_t)N * N_VERTS * 3;

    if (ws_size >= need) {
        int tot_pd = 621 * N_VERTS;
        int tot_w  = 24 * N_VERTS;
        t_transpose<<<(tot_pd + 255) / 256, 256, 0, stream>>>(posedirs, pd_t, 621, tot_pd);
        t_transpose<<<(tot_w + 255) / 256, 256, 0, stream>>>(weights, w_t, 24, tot_w);
        t_transpose<<<(tot_w + 255) / 256, 256, 0, stream>>>(jointreg, jr_t, 24, tot_w);
        k3_skin_t<<<g3, 256, 0, stream>>>(betas, trans, v_templ, shapedirs,
                                          pd_t, w_t, G_ws, lrot, out);
        k4_joints_t<<<N, 256, 0, stream>>>(out, jr_t, outj);
    } else {
        k3_skin<<<g3, 256, 0, stream>>>(betas, trans, v_templ, shapedirs,
                                        posedirs, weights, G_ws, lrot, out);
        k4_joints<<<N, 256, 0, stream>>>(out, jointreg, outj);
    }
}

// Round 9
// 338.074 us; speedup vs baseline: 1.6796x; 1.1634x over previous
//
#include <hip/hip_runtime.h>
#include <hip/hip_fp16.h>
#include <math.h>

#define NJ 24
#define NV 6890
#define NVP 6912          // padded vertex count (27*256)
#define NP 207
#define NPP 208           // padded pose-feature count (lrot[207] = 0)

__constant__ int c_par[24] = {0, 0, 0, 0, 1, 2, 3, 4, 5, 6, 7, 8, 9, 9, 9,
                              12, 13, 14, 16, 17, 18, 19, 20, 21};

// ---------------------------------------------------------------------------
// T: one fused pack/transpose kernel.
//  pd  [NV][3][207] -> pd_h  fp16 [3][208][NVP]   (row 207 + pad verts unwritten)
//  W   [NV][24]     -> w_t   f32  [24][NVP]
//  jr  [NV][24]     -> jr_t  f32  [24][NVP]
//  sd  [NV][30]     -> sd_t  f32  [30][NVP]
//  vt  [NV][3]      -> vt_t  f32  [3][NVP]
__global__ void t_pack(const float* __restrict__ pd,
                       const float* __restrict__ W,
                       const float* __restrict__ jr,
                       const float* __restrict__ sd,
                       const float* __restrict__ vt,
                       __half* __restrict__ pd_h,
                       float* __restrict__ w_t,
                       float* __restrict__ jr_t,
                       float* __restrict__ sd_t,
                       float* __restrict__ vt_t) {
    int idx = blockIdx.x * 256 + threadIdx.x;
    const int PD_N = 3 * NP * NVP;
    if (idx < PD_N) {
        int c = idx / (NP * NVP);
        int r = idx % (NP * NVP);
        int p = r / NVP, v = r % NVP;
        if (v < NV)
            pd_h[((size_t)c * NPP + p) * NVP + v] =
                __float2half(pd[(size_t)v * 621 + c * NP + p]);
        return;
    }
    idx -= PD_N;
    if (idx < 24 * NVP) {
        int j = idx / NVP, v = idx % NVP;
        if (v < NV) w_t[(size_t)j * NVP + v] = W[(size_t)v * 24 + j];
        return;
    }
    idx -= 24 * NVP;
    if (idx < 24 * NVP) {
        int j = idx / NVP, v = idx % NVP;
        if (v < NV) jr_t[(size_t)j * NVP + v] = jr[(size_t)v * 24 + j];
        return;
    }
    idx -= 24 * NVP;
    if (idx < 30 * NVP) {
        int r = idx / NVP, v = idx % NVP;
        if (v < NV) sd_t[(size_t)r * NVP + v] = sd[(size_t)v * 30 + r];
        return;
    }
    idx -= 30 * NVP;
    if (idx < 3 * NVP) {
        int c = idx / NVP, v = idx % NVP;
        if (v < NV) vt_t[(size_t)c * NVP + v] = vt[(size_t)v * 3 + c];
    }
}

// ---------------------------------------------------------------------------
// K1: fold J_regressor into shapedirs / v_template (coalesced via sd_t/vt_t).
__global__ void k1_regress(const float* __restrict__ Jreg,
                           const float* __restrict__ sd_t,
                           const float* __restrict__ vt_t,
                           float* __restrict__ SD_J,
                           float* __restrict__ Jt) {
    int j = blockIdx.x / 3;
    int c = blockIdx.x % 3;
    float acc[11];
#pragma unroll
    for (int k = 0; k < 11; k++) acc[k] = 0.f;

    for (int v = threadIdx.x; v < NV; v += 256) {
        float r = Jreg[j * NV + v];
#pragma unroll
        for (int k = 0; k < 10; k++)
            acc[k] += r * sd_t[(size_t)(c * 10 + k) * NVP + v];
        acc[10] += r * vt_t[(size_t)c * NVP + v];
    }
#pragma unroll
    for (int k = 0; k < 11; k++) {
        float x = acc[k];
        for (int off = 32; off > 0; off >>= 1) x += __shfl_down(x, off);
        acc[k] = x;
    }
    __shared__ float red[4][11];
    int lane = threadIdx.x & 63, wid = threadIdx.x >> 6;
    if (lane == 0) {
#pragma unroll
        for (int k = 0; k < 11; k++) red[wid][k] = acc[k];
    }
    __syncthreads();
    if (threadIdx.x == 0) {
#pragma unroll
        for (int k = 0; k < 11; k++) {
            float s = red[0][k] + red[1][k] + red[2][k] + red[3][k];
            if (k < 10) SD_J[(j * 3 + c) * 10 + k] = s;
            else        Jt[j * 3 + c] = s;
        }
    }
}

// ---------------------------------------------------------------------------
// K2: per-sample joints + rodrigues + FK.  grid = N, block = 64.
__global__ void k2_fk(const float* __restrict__ betas,
                      const float* __restrict__ thetas,
                      const float* __restrict__ SD_J,
                      const float* __restrict__ Jt,
                      float* __restrict__ Gout,
                      float* __restrict__ lrot) {
    int n = blockIdx.x;
    int j = threadIdx.x;

    __shared__ float bsh[10];
    __shared__ float Jl[24][3];
    __shared__ float A[24][12];
    __shared__ float Gs[24][12];

    if (threadIdx.x < 10) bsh[threadIdx.x] = betas[n * 10 + threadIdx.x];
    if (threadIdx.x == 0) lrot[(size_t)n * NPP + 207] = 0.f;  // pad for b128 path
    __syncthreads();

    if (j < 24) {
#pragma unroll
        for (int c = 0; c < 3; c++) {
            float s = Jt[j * 3 + c];
            const float* sp = SD_J + (j * 3 + c) * 10;
#pragma unroll
            for (int k = 0; k < 10; k++) s += bsh[k] * sp[k];
            Jl[j][c] = s;
        }
    }
    __syncthreads();

    if (j < 24) {
        float rx = thetas[n * 72 + j * 3 + 0];
        float ry = thetas[n * 72 + j * 3 + 1];
        float rz = thetas[n * 72 + j * 3 + 2];
        float th = sqrtf(rx * rx + ry * ry + rz * rz) + 1e-8f;
        float inv = 1.f / th;
        float hx = rx * inv, hy = ry * inv, hz = rz * inv;
        float ct = cosf(th), st = sinf(th), omc = 1.f - ct;
        float R[3][3];
        R[0][0] = ct + omc * hx * hx;
        R[0][1] = omc * hx * hy - st * hz;
        R[0][2] = omc * hx * hz + st * hy;
        R[1][0] = omc * hx * hy + st * hz;
        R[1][1] = ct + omc * hy * hy;
        R[1][2] = omc * hy * hz - st * hx;
        R[2][0] = omc * hx * hz - st * hy;
        R[2][1] = omc * hy * hz + st * hx;
        R[2][2] = ct + omc * hz * hz;

        if (j >= 1) {
            float* lp = lrot + (size_t)n * NPP + (j - 1) * 9;
#pragma unroll
            for (int r = 0; r < 3; r++)
#pragma unroll
                for (int c = 0; c < 3; c++)
                    lp[r * 3 + c] = R[r][c] - ((r == c) ? 1.f : 0.f);
        }
        float tx, ty, tz;
        if (j == 0) { tx = Jl[0][0]; ty = Jl[0][1]; tz = Jl[0][2]; }
        else {
            int p = c_par[j];
            tx = Jl[j][0] - Jl[p][0];
            ty = Jl[j][1] - Jl[p][1];
            tz = Jl[j][2] - Jl[p][2];
        }
#pragma unroll
        for (int r = 0; r < 3; r++) {
            A[j][r * 4 + 0] = R[r][0];
            A[j][r * 4 + 1] = R[r][1];
            A[j][r * 4 + 2] = R[r][2];
        }
        A[j][3] = tx; A[j][7] = ty; A[j][11] = tz;
    }
    __syncthreads();

    if (threadIdx.x == 0) {
#pragma unroll
        for (int q = 0; q < 12; q++) Gs[0][q] = A[0][q];
        for (int i = 1; i < 24; i++) {
            int p = c_par[i];
#pragma unroll
            for (int r = 0; r < 3; r++) {
                float g0 = Gs[p][r * 4 + 0], g1 = Gs[p][r * 4 + 1];
                float g2 = Gs[p][r * 4 + 2], g3 = Gs[p][r * 4 + 3];
#pragma unroll
                for (int c = 0; c < 4; c++) {
                    float s = g0 * A[i][0 * 4 + c] + g1 * A[i][1 * 4 + c] +
                              g2 * A[i][2 * 4 + c];
                    if (c == 3) s += g3;
                    Gs[i][r * 4 + c] = s;
                }
            }
        }
    }
    __syncthreads();

    if (j < 24) {
        float jx = Jl[j][0], jy = Jl[j][1], jz = Jl[j][2];
        float* gp = Gout + (size_t)n * 288 + j * 12;
#pragma unroll
        for (int r = 0; r < 3; r++) {
            float r0 = Gs[j][r * 4 + 0], r1 = Gs[j][r * 4 + 1];
            float r2 = Gs[j][r * 4 + 2], t = Gs[j][r * 4 + 3];
            gp[r * 4 + 0] = r0;
            gp[r * 4 + 1] = r1;
            gp[r * 4 + 2] = r2;
            gp[r * 4 + 3] = t - (r0 * jx + r1 * jy + r2 * jz);
        }
    }
}

// ---------------------------------------------------------------------------
// K3v: skinning, 4 verts/thread.  Block = 4 waves x (64 lanes x 4 verts);
// wave w handles samples s0=w*4..w*4+3; all waves share the 256-vert tile.
// grid = (N/16, NVP/256 = 27).
__global__ void __launch_bounds__(256)
k3v(const float* __restrict__ betas,
    const float* __restrict__ trans,
    const float* __restrict__ vt_t,
    const float* __restrict__ sd_t,
    const __half* __restrict__ pd_h,
    const float* __restrict__ w_t,
    const float* __restrict__ G_ws,
    const float* __restrict__ lrot_ws,
    float* __restrict__ out) {
    __shared__ float Llrot[16][NPP];
    __shared__ float Lg[16][288];
    __shared__ float Lbet[16][10];
    __shared__ float Ltr[16][3];

    const int tid = threadIdx.x;
    const int nbase = blockIdx.x * 16;
    const int vbase = blockIdx.y * 256;

    for (int idx = tid; idx < 16 * NPP; idx += 256) {
        int s = idx / NPP, p = idx % NPP;
        Llrot[s][p] = lrot_ws[(size_t)(nbase + s) * NPP + p];
    }
    for (int idx = tid; idx < 16 * 288; idx += 256) {
        int s = idx / 288, q = idx % 288;
        Lg[s][q] = G_ws[(size_t)(nbase + s) * 288 + q];
    }
    if (tid < 160) Lbet[tid / 10][tid % 10] = betas[(nbase + tid / 10) * 10 + tid % 10];
    if (tid < 48)  Ltr[tid / 3][tid % 3] = trans[(nbase + tid / 3) * 3 + tid % 3];
    __syncthreads();

    const int lane = tid & 63;
    const int s0 = (tid >> 6) * 4;
    const int v4 = vbase + lane * 4;

    float acc[4][3][4];
#pragma unroll
    for (int c = 0; c < 3; c++) {
        float4 tv = *(const float4*)(vt_t + (size_t)c * NVP + v4);
#pragma unroll
        for (int s = 0; s < 4; s++) {
            acc[s][c][0] = tv.x; acc[s][c][1] = tv.y;
            acc[s][c][2] = tv.z; acc[s][c][3] = tv.w;
        }
    }
    // shape blend
#pragma unroll
    for (int k = 0; k < 10; k++) {
        float4 sv[3];
#pragma unroll
        for (int c = 0; c < 3; c++)
            sv[c] = *(const float4*)(sd_t + (size_t)(c * 10 + k) * NVP + v4);
#pragma unroll
        for (int s = 0; s < 4; s++) {
            float b = Lbet[s0 + s][k];
#pragma unroll
            for (int c = 0; c < 3; c++) {
                acc[s][c][0] += b * sv[c].x; acc[s][c][1] += b * sv[c].y;
                acc[s][c][2] += b * sv[c].z; acc[s][c][3] += b * sv[c].w;
            }
        }
    }
    // pose blend: 52 quads of p (l[207] = 0 covers the pad)
    for (int ph = 0; ph < 52; ph++) {
        const int p0 = ph * 4;
        float4 pv[3][4];
#pragma unroll
        for (int c = 0; c < 3; c++)
#pragma unroll
            for (int pp = 0; pp < 4; pp++) {
                uint2 u = *(const uint2*)(pd_h + ((size_t)c * NPP + p0 + pp) * NVP + v4);
                __half2 a = *(__half2*)&u.x;
                __half2 b = *(__half2*)&u.y;
                float2 fa = __half22float2(a), fb = __half22float2(b);
                pv[c][pp] = make_float4(fa.x, fa.y, fb.x, fb.y);
            }
#pragma unroll
        for (int s = 0; s < 4; s++) {
            float4 l = ((const float4*)&Llrot[s0 + s][0])[ph];
#pragma unroll
            for (int c = 0; c < 3; c++) {
                acc[s][c][0] += l.x * pv[c][0].x + l.y * pv[c][1].x + l.z * pv[c][2].x + l.w * pv[c][3].x;
                acc[s][c][1] += l.x * pv[c][0].y + l.y * pv[c][1].y + l.z * pv[c][2].y + l.w * pv[c][3].y;
                acc[s][c][2] += l.x * pv[c][0].z + l.y * pv[c][1].z + l.z * pv[c][2].z + l.w * pv[c][3].z;
                acc[s][c][3] += l.x * pv[c][0].w + l.y * pv[c][1].w + l.z * pv[c][2].w + l.w * pv[c][3].w;
            }
        }
    }
    // LBS: out = sum_j w_j * (G_j . vp)  — G read once per (s,j), shared by 4 verts
    float o[4][3][4];
#pragma unroll
    for (int s = 0; s < 4; s++)
#pragma unroll
        for (int c = 0; c < 3; c++)
#pragma unroll
            for (int i = 0; i < 4; i++) o[s][c][i] = 0.f;

    for (int j = 0; j < NJ; j++) {
        float4 w4 = *(const float4*)(w_t + (size_t)j * NVP + v4);
        float wv[4] = {w4.x, w4.y, w4.z, w4.w};
#pragma unroll
        for (int s = 0; s < 4; s++) {
            const float4* g4 = (const float4*)&Lg[s0 + s][j * 12];
            float4 g0 = g4[0], g1 = g4[1], g2 = g4[2];
#pragma unroll
            for (int i = 0; i < 4; i++) {
                float x = acc[s][0][i], y = acc[s][1][i], z = acc[s][2][i];
                float r0 = g0.x * x + g0.y * y + g0.z * z + g0.w;
                float r1 = g1.x * x + g1.y * y + g1.z * z + g1.w;
                float r2 = g2.x * x + g2.y * y + g2.z * z + g2.w;
                o[s][0][i] += wv[i] * r0;
                o[s][1][i] += wv[i] * r1;
                o[s][2][i] += wv[i] * r2;
            }
        }
    }
    // epilogue: add trans, store (guard pad verts)
#pragma unroll
    for (int s = 0; s < 4; s++) {
        int n = nbase + s0 + s;
        float t0 = Ltr[s0 + s][0], t1 = Ltr[s0 + s][1], t2 = Ltr[s0 + s][2];
        float* op = out + ((size_t)n * NV + v4) * 3;
#pragma unroll
        for (int i = 0; i < 4; i++) {
            if (v4 + i < NV) {
                op[i * 3 + 0] = o[s][0][i] + t0;
                op[i * 3 + 1] = o[s][1][i] + t1;
                op[i * 3 + 2] = o[s][2][i] + t2;
            }
        }
    }
}

// ---------------------------------------------------------------------------
// K4: joints[n][j][c] = sum_v result[n][v][c] * jr_t[j][v].  grid = N.
__global__ void k4_joints_t(const float* __restrict__ result,
                            const float* __restrict__ jr_t,
                            float* __restrict__ outj) {
    int n = blockIdx.x;
    int tid = threadIdx.x;
    float acc[72];
#pragma unroll
    for (int q = 0; q < 72; q++) acc[q] = 0.f;

    for (int v = tid; v < NV; v += 256) {
        const float* rp = result + ((size_t)n * NV + v) * 3;
        float r0 = rp[0], r1 = rp[1], r2 = rp[2];
#pragma unroll
        for (int j = 0; j < 24; j++) {
            float wv = jr_t[(size_t)j * NVP + v];
            acc[j * 3 + 0] += wv * r0;
            acc[j * 3 + 1] += wv * r1;
            acc[j * 3 + 2] += wv * r2;
        }
    }
#pragma unroll
    for (int q = 0; q < 72; q++) {
        float x = acc[q];
        for (int off = 32; off > 0; off >>= 1) x += __shfl_down(x, off);
        acc[q] = x;
    }
    __shared__ float red[4][72];
    int lane = tid & 63, wid = tid >> 6;
    if (lane == 0) {
#pragma unroll
        for (int q = 0; q < 72; q++) red[wid][q] = acc[q];
    }
    __syncthreads();
    if (tid < 72) {
        float s = red[0][tid] + red[1][tid] + red[2][tid] + red[3][tid];
        outj[(size_t)n * 72 + tid] = s;
    }
}

// ---------------------------------------------------------------------------
extern "C" void kernel_launch(void* const* d_in, const int* in_sizes, int n_in,
                              void* d_out, int out_size, void* d_ws, size_t ws_size,
                              hipStream_t stream) {
    const float* betas     = (const float*)d_in[0];
    const float* thetas    = (const float*)d_in[1];
    const float* trans     = (const float*)d_in[2];
    const float* v_templ   = (const float*)d_in[3];
    const float* shapedirs = (const float*)d_in[4];
    const float* posedirs  = (const float*)d_in[5];
    const float* Jreg      = (const float*)d_in[6];
    const float* jointreg  = (const float*)d_in[7];
    const float* weights   = (const float*)d_in[8];

    float* out = (float*)d_out;       // fp32: result [N,V,3] then joints [N,24,3]
    const int N = in_sizes[0] / 10;   // 512

    // ws layout (floats, pd_h region is fp16)
    float* ws    = (float*)d_ws;
    float* SD_J  = ws;                                   // 720
    float* Jt    = ws + 720;                             // 72  (+8 pad)
    float* G_ws  = ws + 800;                             // N*288
    float* lrot  = G_ws + (size_t)N * 288;               // N*208
    float* w_t   = lrot + (size_t)N * NPP;               // 24*NVP
    float* jr_t  = w_t + 24 * NVP;                       // 24*NVP
    float* sd_t  = jr_t + 24 * NVP;                      // 30*NVP
    float* vt_t  = sd_t + 30 * NVP;                      // 3*NVP
    __half* pd_h = (__half*)(vt_t + 3 * NVP);            // 3*208*NVP halves

    int t_total = (3 * NP + 24 + 24 + 30 + 3) * NVP;     // 4,852,224
    t_pack<<<(t_total + 255) / 256, 256, 0, stream>>>(
        posedirs, weights, jointreg, shapedirs, v_templ,
        pd_h, w_t, jr_t, sd_t, vt_t);

    k1_regress<<<72, 256, 0, stream>>>(Jreg, sd_t, vt_t, SD_J, Jt);
    k2_fk<<<N, 64, 0, stream>>>(betas, thetas, SD_J, Jt, G_ws, lrot);

    dim3 g3(N / 16, NVP / 256);   // (32, 27)
    k3v<<<g3, 256, 0, stream>>>(betas, trans, vt_t, sd_t, pd_h, w_t,
                                G_ws, lrot, out);

    float* outj = out + (size_t)N * NV * 3;
    k4_joints_t<<<N, 256, 0, stream>>>(out, jr_t, outj);
}

// Round 10
// 249.923 us; speedup vs baseline: 2.2720x; 1.3527x over previous
//
#include <hip/hip_runtime.h>
#include <hip/hip_bf16.h>
#include <math.h>

#define NJ 24
#define NV 6890
#define NVP 6912          // padded vertex count (27*256)
#define NPRIME 20736      // 3*NVP, GEMM N dimension
#define NT 1296           // NPRIME/16 n-tiles
#define KDIM 224          // padded K: [0..9]=betas/sd, [10]=1/vt, [11..217]=lrot/pd, rest 0

__constant__ int c_par[24] = {0, 0, 0, 0, 1, 2, 3, 4, 5, 6, 7, 8, 9, 9, 9,
                              12, 13, 14, 16, 17, 18, 19, 20, 21};

typedef __attribute__((ext_vector_type(8))) short short8;
typedef __attribute__((ext_vector_type(4))) float float4v;

__device__ __forceinline__ unsigned short f2b(float x) {
    __hip_bfloat16 h = __float2bfloat16(x);
    return *reinterpret_cast<unsigned short*>(&h);
}
__device__ __forceinline__ float b2f(unsigned short u) {
    unsigned int w = ((unsigned int)u) << 16;
    return __uint_as_float(w);
}

// ---------------------------------------------------------------------------
// T: pack kernel.
//  B2  : MFMA-tiled bf16 B''[kc][nt][ln16][kk32]; element (k, n'=c*NVP+v):
//        k<10 -> sd[v][c][k]; k==10 -> vt[v][c]; 11<=k<218 -> pd[v][c][k-11]; else 0.
//        Consecutive elements <-> consecutive p: reads AND writes coalesced.
//  w_t / jr_t : f32 [24][NVP];  sd_t: f32 [30][NVP]; vt_t: f32 [3][NVP]
__global__ void t_pack(const float* __restrict__ pd,
                       const float* __restrict__ W,
                       const float* __restrict__ jr,
                       const float* __restrict__ sd,
                       const float* __restrict__ vt,
                       unsigned short* __restrict__ B2,
                       float* __restrict__ w_t,
                       float* __restrict__ jr_t,
                       float* __restrict__ sd_t,
                       float* __restrict__ vt_t) {
    int idx = blockIdx.x * 256 + threadIdx.x;
    const int B2_N = 7 * NT * 16 * 32;        // 4,644,864
    if (idx < B2_N) {
        int kk = idx & 31;
        int ln = (idx >> 5) & 15;
        int rest = idx >> 9;                  // nt + NT*kc
        int nt = rest % NT, kc = rest / NT;
        int k = kc * 32 + kk;
        int np = nt * 16 + ln;
        int c = np / NVP, v = np - c * NVP;
        float val = 0.f;
        if (v < NV) {
            if (k < 10)       val = sd[(size_t)v * 30 + c * 10 + k];
            else if (k == 10) val = vt[v * 3 + c];
            else if (k < 218) val = pd[(size_t)v * 621 + c * 207 + (k - 11)];
        }
        B2[idx] = f2b(val);
        return;
    }
    idx -= B2_N;
    if (idx < 24 * NVP) {
        int j = idx / NVP, v = idx % NVP;
        if (v < NV) w_t[(size_t)j * NVP + v] = W[(size_t)v * 24 + j];
        return;
    }
    idx -= 24 * NVP;
    if (idx < 24 * NVP) {
        int j = idx / NVP, v = idx % NVP;
        if (v < NV) jr_t[(size_t)j * NVP + v] = jr[(size_t)v * 24 + j];
        return;
    }
    idx -= 24 * NVP;
    if (idx < 30 * NVP) {
        int r = idx / NVP, v = idx % NVP;
        if (v < NV) sd_t[(size_t)r * NVP + v] = sd[(size_t)v * 30 + r];
        return;
    }
    idx -= 30 * NVP;
    if (idx < 3 * NVP) {
        int c = idx / NVP, v = idx % NVP;
        if (v < NV) vt_t[(size_t)c * NVP + v] = vt[(size_t)v * 3 + c];
    }
}

// ---------------------------------------------------------------------------
// K1: fold J_regressor into shapedirs / v_template (coalesced, fp32).
__global__ void k1_regress(const float* __restrict__ Jreg,
                           const float* __restrict__ sd_t,
                           const float* __restrict__ vt_t,
                           float* __restrict__ SD_J,
                           float* __restrict__ Jt) {
    int j = blockIdx.x / 3;
    int c = blockIdx.x % 3;
    float acc[11];
#pragma unroll
    for (int k = 0; k < 11; k++) acc[k] = 0.f;

    for (int v = threadIdx.x; v < NV; v += 256) {
        float r = Jreg[j * NV + v];
#pragma unroll
        for (int k = 0; k < 10; k++)
            acc[k] += r * sd_t[(size_t)(c * 10 + k) * NVP + v];
        acc[10] += r * vt_t[(size_t)c * NVP + v];
    }
#pragma unroll
    for (int k = 0; k < 11; k++) {
        float x = acc[k];
        for (int off = 32; off > 0; off >>= 1) x += __shfl_down(x, off);
        acc[k] = x;
    }
    __shared__ float red[4][11];
    int lane = threadIdx.x & 63, wid = threadIdx.x >> 6;
    if (lane == 0) {
#pragma unroll
        for (int k = 0; k < 11; k++) red[wid][k] = acc[k];
    }
    __syncthreads();
    if (threadIdx.x == 0) {
#pragma unroll
        for (int k = 0; k < 11; k++) {
            float s = red[0][k] + red[1][k] + red[2][k] + red[3][k];
            if (k < 10) SD_J[(j * 3 + c) * 10 + k] = s;
            else        Jt[j * 3 + c] = s;
        }
    }
}

// ---------------------------------------------------------------------------
// K2: per-sample joints + rodrigues + FK.  grid = N, block = 64.
__global__ void k2_fk(const float* __restrict__ betas,
                      const float* __restrict__ thetas,
                      const float* __restrict__ SD_J,
                      const float* __restrict__ Jt,
                      float* __restrict__ Gout,
                      float* __restrict__ lrot) {
    int n = blockIdx.x;
    int j = threadIdx.x;

    __shared__ float bsh[10];
    __shared__ float Jl[24][3];
    __shared__ float A[24][12];
    __shared__ float Gs[24][12];

    if (threadIdx.x < 10) bsh[threadIdx.x] = betas[n * 10 + threadIdx.x];
    if (threadIdx.x == 0) lrot[(size_t)n * 208 + 207] = 0.f;
    __syncthreads();

    if (j < 24) {
#pragma unroll
        for (int c = 0; c < 3; c++) {
            float s = Jt[j * 3 + c];
            const float* sp = SD_J + (j * 3 + c) * 10;
#pragma unroll
            for (int k = 0; k < 10; k++) s += bsh[k] * sp[k];
            Jl[j][c] = s;
        }
    }
    __syncthreads();

    if (j < 24) {
        float rx = thetas[n * 72 + j * 3 + 0];
        float ry = thetas[n * 72 + j * 3 + 1];
        float rz = thetas[n * 72 + j * 3 + 2];
        float th = sqrtf(rx * rx + ry * ry + rz * rz) + 1e-8f;
        float inv = 1.f / th;
        float hx = rx * inv, hy = ry * inv, hz = rz * inv;
        float ct = cosf(th), st = sinf(th), omc = 1.f - ct;
        float R[3][3];
        R[0][0] = ct + omc * hx * hx;
        R[0][1] = omc * hx * hy - st * hz;
        R[0][2] = omc * hx * hz + st * hy;
        R[1][0] = omc * hx * hy + st * hz;
        R[1][1] = ct + omc * hy * hy;
        R[1][2] = omc * hy * hz - st * hx;
        R[2][0] = omc * hx * hz - st * hy;
        R[2][1] = omc * hy * hz + st * hx;
        R[2][2] = ct + omc * hz * hz;

        if (j >= 1) {
            float* lp = lrot + (size_t)n * 208 + (j - 1) * 9;
#pragma unroll
            for (int r = 0; r < 3; r++)
#pragma unroll
                for (int c = 0; c < 3; c++)
                    lp[r * 3 + c] = R[r][c] - ((r == c) ? 1.f : 0.f);
        }
        float tx, ty, tz;
        if (j == 0) { tx = Jl[0][0]; ty = Jl[0][1]; tz = Jl[0][2]; }
        else {
            int p = c_par[j];
            tx = Jl[j][0] - Jl[p][0];
            ty = Jl[j][1] - Jl[p][1];
            tz = Jl[j][2] - Jl[p][2];
        }
#pragma unroll
        for (int r = 0; r < 3; r++) {
            A[j][r * 4 + 0] = R[r][0];
            A[j][r * 4 + 1] = R[r][1];
            A[j][r * 4 + 2] = R[r][2];
        }
        A[j][3] = tx; A[j][7] = ty; A[j][11] = tz;
    }
    __syncthreads();

    if (threadIdx.x == 0) {
#pragma unroll
        for (int q = 0; q < 12; q++) Gs[0][q] = A[0][q];
        for (int i = 1; i < 24; i++) {
            int p = c_par[i];
#pragma unroll
            for (int r = 0; r < 3; r++) {
                float g0 = Gs[p][r * 4 + 0], g1 = Gs[p][r * 4 + 1];
                float g2 = Gs[p][r * 4 + 2], g3 = Gs[p][r * 4 + 3];
#pragma unroll
                for (int c = 0; c < 4; c++) {
                    float s = g0 * A[i][0 * 4 + c] + g1 * A[i][1 * 4 + c] +
                              g2 * A[i][2 * 4 + c];
                    if (c == 3) s += g3;
                    Gs[i][r * 4 + c] = s;
                }
            }
        }
    }
    __syncthreads();

    if (j < 24) {
        float jx = Jl[j][0], jy = Jl[j][1], jz = Jl[j][2];
        float* gp = Gout + (size_t)n * 288 + j * 12;
#pragma unroll
        for (int r = 0; r < 3; r++) {
            float r0 = Gs[j][r * 4 + 0], r1 = Gs[j][r * 4 + 1];
            float r2 = Gs[j][r * 4 + 2], t = Gs[j][r * 4 + 3];
            gp[r * 4 + 0] = r0;
            gp[r * 4 + 1] = r1;
            gp[r * 4 + 2] = r2;
            gp[r * 4 + 3] = t - (r0 * jx + r1 * jy + r2 * jz);
        }
    }
}

// ---------------------------------------------------------------------------
// K2b: pack A_bf [512][224] bf16 feature rows: [betas(10) | 1 | lrot(207) | 0...].
__global__ void k2b_packA(const float* __restrict__ betas,
                          const float* __restrict__ lrot,
                          unsigned short* __restrict__ A_bf) {
    int n = blockIdx.x;
    for (int k = threadIdx.x; k < KDIM; k += 64) {
        float val;
        if (k < 10)       val = betas[n * 10 + k];
        else if (k == 10) val = 1.f;
        else if (k < 218) val = lrot[(size_t)n * 208 + (k - 11)];
        else              val = 0.f;
        A_bf[(size_t)n * KDIM + k] = f2b(val);
    }
}

// ---------------------------------------------------------------------------
// K3G: MFMA GEMM  v_posed[m=512][n'=20736] = A[512][224] x B[224][20736].
// block = 4 waves, each wave owns m-tile m0 = blockIdx.y*64 + wave*16,
// iterates 12 n-tiles.  A-frags register-resident across all K.
// C layout (verified m89/m91): col = lane&15 (n), row = (lane>>4)*4 + reg (m).
__global__ void __launch_bounds__(256)
k3g(const unsigned short* __restrict__ A_bf,
    const unsigned short* __restrict__ B2,
    unsigned short* __restrict__ vposed) {
    const int wave = threadIdx.x >> 6, lane = threadIdx.x & 63;
    const int ln = lane & 15, q = lane >> 4;
    const int m0 = blockIdx.y * 64 + wave * 16;
    const int nt0 = blockIdx.x * 12;

    short8 a[7];
    {
        const int row = m0 + ln;
#pragma unroll
        for (int kc = 0; kc < 7; kc++)
            a[kc] = *(const short8*)(A_bf + (size_t)row * KDIM + kc * 32 + q * 8);
    }
    for (int t = 0; t < 12; t++) {
        const int nt = nt0 + t;
        float4v acc = {0.f, 0.f, 0.f, 0.f};
#pragma unroll
        for (int kc = 0; kc < 7; kc++) {
            short8 b = *(const short8*)(B2 +
                (((size_t)kc * NT + nt) * 16 + ln) * 32 + q * 8);
            acc = __builtin_amdgcn_mfma_f32_16x16x32_bf16(a[kc], b, acc, 0, 0, 0);
        }
        const int np = nt * 16 + ln;
#pragma unroll
        for (int r = 0; r < 4; r++) {
            int m = m0 + q * 4 + r;
            vposed[(size_t)m * NPRIME + np] = f2b(acc[r]);
        }
    }
}

// ---------------------------------------------------------------------------
// K3L: LBS only.  block = 4 waves x (64 lanes x 4 verts); wave w -> samples
// s0 = w*4..w*4+3.  grid = (N/16, NVP/256 = 27).  Reads v_posed coalesced.
__global__ void __launch_bounds__(256)
k3l(const float* __restrict__ trans,
    const unsigned short* __restrict__ vposed,
    const float* __restrict__ w_t,
    const float* __restrict__ G_ws,
    float* __restrict__ out) {
    __shared__ float Lg[16][288];
    __shared__ float Ltr[16][3];

    const int tid = threadIdx.x;
    const int nbase = blockIdx.x * 16;
    const int vbase = blockIdx.y * 256;

    for (int idx = tid; idx < 16 * 288; idx += 256) {
        int s = idx / 288, qq = idx % 288;
        Lg[s][qq] = G_ws[(size_t)(nbase + s) * 288 + qq];
    }
    if (tid < 48) Ltr[tid / 3][tid % 3] = trans[(nbase + tid / 3) * 3 + tid % 3];
    __syncthreads();

    const int lane = tid & 63;
    const int s0 = (tid >> 6) * 4;
    const int v4 = vbase + lane * 4;

    // load v_posed bf16x4 per (sample, coord)
    float vp[4][3][4];
#pragma unroll
    for (int s = 0; s < 4; s++) {
        int n = nbase + s0 + s;
#pragma unroll
        for (int c = 0; c < 3; c++) {
            uint2 u = *(const uint2*)(vposed + (size_t)n * NPRIME + c * NVP + v4);
            vp[s][c][0] = b2f((unsigned short)(u.x & 0xFFFF));
            vp[s][c][1] = b2f((unsigned short)(u.x >> 16));
            vp[s][c][2] = b2f((unsigned short)(u.y & 0xFFFF));
            vp[s][c][3] = b2f((unsigned short)(u.y >> 16));
        }
    }

    float o[4][3][4];
#pragma unroll
    for (int s = 0; s < 4; s++)
#pragma unroll
        for (int c = 0; c < 3; c++)
#pragma unroll
            for (int i = 0; i < 4; i++) o[s][c][i] = 0.f;

    for (int j = 0; j < NJ; j++) {
        float4 w4 = *(const float4*)(w_t + (size_t)j * NVP + v4);
        float wv[4] = {w4.x, w4.y, w4.z, w4.w};
#pragma unroll
        for (int s = 0; s < 4; s++) {
            const float4* g4 = (const float4*)&Lg[s0 + s][j * 12];
            float4 g0 = g4[0], g1 = g4[1], g2 = g4[2];
#pragma unroll
            for (int i = 0; i < 4; i++) {
                float x = vp[s][0][i], y = vp[s][1][i], z = vp[s][2][i];
                float r0 = g0.x * x + g0.y * y + g0.z * z + g0.w;
                float r1 = g1.x * x + g1.y * y + g1.z * z + g1.w;
                float r2 = g2.x * x + g2.y * y + g2.z * z + g2.w;
                o[s][0][i] += wv[i] * r0;
                o[s][1][i] += wv[i] * r1;
                o[s][2][i] += wv[i] * r2;
            }
        }
    }
#pragma unroll
    for (int s = 0; s < 4; s++) {
        int n = nbase + s0 + s;
        float t0 = Ltr[s0 + s][0], t1 = Ltr[s0 + s][1], t2 = Ltr[s0 + s][2];
        float* op = out + ((size_t)n * NV + v4) * 3;
#pragma unroll
        for (int i = 0; i < 4; i++) {
            if (v4 + i < NV) {
                op[i * 3 + 0] = o[s][0][i] + t0;
                op[i * 3 + 1] = o[s][1][i] + t1;
                op[i * 3 + 2] = o[s][2][i] + t2;
            }
        }
    }
}

// ---------------------------------------------------------------------------
// K4: joints[n][j][c] = sum_v result[n][v][c] * jr_t[j][v].  grid = N.
__global__ void k4_joints_t(const float* __restrict__ result,
                            const float* __restrict__ jr_t,
                            float* __restrict__ outj) {
    int n = blockIdx.x;
    int tid = threadIdx.x;
    float acc[72];
#pragma unroll
    for (int q = 0; q < 72; q++) acc[q] = 0.f;

    for (int v = tid; v < NV; v += 256) {
        const float* rp = result + ((size_t)n * NV + v) * 3;
        float r0 = rp[0], r1 = rp[1], r2 = rp[2];
#pragma unroll
        for (int j = 0; j < 24; j++) {
            float wv = jr_t[(size_t)j * NVP + v];
            acc[j * 3 + 0] += wv * r0;
            acc[j * 3 + 1] += wv * r1;
            acc[j * 3 + 2] += wv * r2;
        }
    }
#pragma unroll
    for (int q = 0; q < 72; q++) {
        float x = acc[q];
        for (int off = 32; off > 0; off >>= 1) x += __shfl_down(x, off);
        acc[q] = x;
    }
    __shared__ float red[4][72];
    int lane = tid & 63, wid = tid >> 6;
    if (lane == 0) {
#pragma unroll
        for (int q = 0; q < 72; q++) red[wid][q] = acc[q];
    }
    __syncthreads();
    if (tid < 72) {
        float s = red[0][tid] + red[1][tid] + red[2][tid] + red[3][tid];
        outj[(size_t)n * 72 + tid] = s;
    }
}

// ---------------------------------------------------------------------------
extern "C" void kernel_launch(void* const* d_in, const int* in_sizes, int n_in,
                              void* d_out, int out_size, void* d_ws, size_t ws_size,
                              hipStream_t stream) {
    const float* betas     = (const float*)d_in[0];
    const float* thetas    = (const float*)d_in[1];
    const float* trans     = (const float*)d_in[2];
    const float* v_templ   = (const float*)d_in[3];
    const float* shapedirs = (const float*)d_in[4];
    const float* posedirs  = (const float*)d_in[5];
    const float* Jreg      = (const float*)d_in[6];
    const float* jointreg  = (const float*)d_in[7];
    const float* weights   = (const float*)d_in[8];

    float* out = (float*)d_out;       // fp32: result [N,V,3] then joints [N,24,3]
    const int N = in_sizes[0] / 10;   // 512

    // ws layout (float offsets; bf16 arrays start at 16B-aligned boundaries)
    float* ws    = (float*)d_ws;
    float* SD_J  = ws;                                   // 720
    float* Jt    = ws + 720;                             // 72 (+pad) -> 800
    float* G_ws  = ws + 800;                             // N*288
    float* lrot  = G_ws + (size_t)N * 288;               // N*208
    float* w_t   = lrot + (size_t)N * 208;               // 24*NVP
    float* jr_t  = w_t + 24 * NVP;                       // 24*NVP
    float* sd_t  = jr_t + 24 * NVP;                      // 30*NVP
    float* vt_t  = sd_t + 30 * NVP;                      // 3*NVP
    unsigned short* A_bf = (unsigned short*)(vt_t + 3 * NVP);       // 512*224
    unsigned short* B2   = A_bf + (size_t)512 * KDIM;               // 7*NT*512
    unsigned short* vpos = B2 + (size_t)7 * NT * 512;               // 512*NPRIME

    const int B2_N = 7 * NT * 16 * 32;
    int t_total = B2_N + (24 + 24 + 30 + 3) * NVP;
    t_pack<<<(t_total + 255) / 256, 256, 0, stream>>>(
        posedirs, weights, jointreg, shapedirs, v_templ,
        B2, w_t, jr_t, sd_t, vt_t);

    k1_regress<<<72, 256, 0, stream>>>(Jreg, sd_t, vt_t, SD_J, Jt);
    k2_fk<<<N, 64, 0, stream>>>(betas, thetas, SD_J, Jt, G_ws, lrot);
    k2b_packA<<<N, 64, 0, stream>>>(betas, lrot, A_bf);

    dim3 gg(NT / 12, N / 64);     // (108, 8)
    k3g<<<gg, 256, 0, stream>>>(A_bf, B2, vpos);

    dim3 gl(N / 16, NVP / 256);   // (32, 27)
    k3l<<<gl, 256, 0, stream>>>(trans, vpos, w_t, G_ws, out);

    float* outj = out + (size_t)N * NV * 3;
    k4_joints_t<<<N, 256, 0, stream>>>(out, jr_t, outj);
}